// Round 1
// baseline (1255.683 us; speedup 1.0000x reference)
//
#include <hip/hip_runtime.h>
#include <math.h>

#define N_NODES 50000
#define N_EDGES 800000
#define NUM_GRAPHS 256
#define C_IN 64
#define C_H 128
#define D_COUNT 9
#define LRELU_SLOPE 0.01f
#define BN_EPS 1e-5f

__device__ __forceinline__ float silu_f(float a) {
    return a / (1.0f + __expf(-a));
}

// h = silu(x @ W_lin + b_lin)   x:[N,64] W:[64,128] -> h:[N,128]
// block: 128 threads, 8 nodes per block
__global__ void lin0_kernel(const float* __restrict__ x, const float* __restrict__ W,
                            const float* __restrict__ b, float* __restrict__ h) {
    __shared__ float xs[8][C_IN];
    const int node0 = blockIdx.x * 8;
    const int t = threadIdx.x;  // 0..127 = output channel
    for (int i = t; i < 8 * C_IN; i += 128)
        xs[i >> 6][i & 63] = x[node0 * C_IN + i];
    __syncthreads();
    float acc[8];
    const float bc = b[t];
#pragma unroll
    for (int n = 0; n < 8; ++n) acc[n] = bc;
    for (int k = 0; k < C_IN; ++k) {
        const float w = W[k * C_H + t];
#pragma unroll
        for (int n = 0; n < 8; ++n) acc[n] += xs[n][k] * w;
    }
#pragma unroll
    for (int n = 0; n < 8; ++n)
        h[(node0 + n) * C_H + t] = silu_f(acc[n]);
}

// Per-edge: radial = silu(rbf(d) @ Wc + bc); msg = h[row]*radial; atomic agg[col] += msg
// block: 256 threads, 256 edges per block.
__global__ void edge_kernel(const float* __restrict__ h, const float* __restrict__ pos,
                            const int* __restrict__ rowi, const int* __restrict__ coli,
                            const float* __restrict__ Wc, const float* __restrict__ bc,
                            float* __restrict__ agg) {
    __shared__ float rbf_s[256][D_COUNT];
    __shared__ int rs_s[256];
    __shared__ int cs_s[256];
    const int t = threadIdx.x;       // 0..255
    const int e0 = blockIdx.x * 256;
    const int c = t & 127;           // channel owned in phase B
    // preload Wc column c + bias (registers, reused for 256 edges)
    float wc[D_COUNT];
#pragma unroll
    for (int k = 0; k < D_COUNT; ++k) wc[k] = Wc[k * C_H + c];
    const float bcc = bc[c];

    // Phase A: one edge per thread -> distance + 9 RBF values into LDS
    {
        const int e = e0 + t;
        const int r = rowi[e];
        const int cl = coli[e];
        rs_s[t] = r;
        cs_s[t] = cl;
        const float dx = pos[r * 3 + 0] - pos[cl * 3 + 0];
        const float dy = pos[r * 3 + 1] - pos[cl * 3 + 1];
        const float dz = pos[r * 3 + 2] - pos[cl * 3 + 2];
        const float d = sqrtf(dx * dx + dy * dy + dz * dz);
#pragma unroll
        for (int k = 0; k < D_COUNT; ++k) {
            const float u = (d - 0.75f * (float)k) * 1.5f;  // sigma = 6/9 -> 1/sigma = 1.5
            rbf_s[t][k] = __expf(-u * u);
        }
    }
    __syncthreads();

    // Phase B: 128 threads per edge (2 edges in flight), channel c per thread
    const int half = t >> 7;
    for (int i = 0; i < 128; ++i) {
        const int el = 2 * i + half;
        const int r = rs_s[el];
        const int cl = cs_s[el];
        float a = bcc;
#pragma unroll
        for (int k = 0; k < D_COUNT; ++k) a += rbf_s[el][k] * wc[k];
        const float radial = a / (1.0f + __expf(-a));
        const float msg = h[r * C_H + c] * radial;
        atomicAdd(&agg[cl * C_H + c], msg);
    }
}

// h = g * lrelu((h+agg) @ Wn + bn) / sqrt(1+eps) + be   (in place)
// block: 128 threads, 16 nodes per block
__global__ void node_kernel(float* __restrict__ h, const float* __restrict__ agg,
                            const float* __restrict__ Wn, const float* __restrict__ bn,
                            const float* __restrict__ g, const float* __restrict__ be) {
    __shared__ float s[16][C_H];
    const int node0 = blockIdx.x * 16;
    const int t = threadIdx.x;  // 0..127 = output channel
    for (int i = t; i < 16 * C_H; i += 128)
        s[i >> 7][i & 127] = h[node0 * C_H + i] + agg[node0 * C_H + i];
    __syncthreads();
    float acc[16];
    const float bnc = bn[t];
#pragma unroll
    for (int n = 0; n < 16; ++n) acc[n] = bnc;
    for (int k = 0; k < C_H; ++k) {
        const float w = Wn[k * C_H + t];
#pragma unroll
        for (int n = 0; n < 16; ++n) acc[n] += s[n][k] * w;
    }
    const float inv = 1.0f / sqrtf(1.0f + BN_EPS);
    const float gc = g[t] * inv;
    const float bec = be[t];
#pragma unroll
    for (int n = 0; n < 16; ++n) {
        float v = acc[n];
        v = v > 0.0f ? v : LRELU_SLOPE * v;
        h[(node0 + n) * C_H + t] = gc * v + bec;
    }
}

// out[g] = sum over nodes with batch==g of h[node]; batch sorted -> run-accumulate
// block: 128 threads, CHUNK nodes per block
__global__ void pool_kernel(const float* __restrict__ h, const int* __restrict__ batch,
                            float* __restrict__ out) {
    const int CHUNK = 250;
    const int n0 = blockIdx.x * CHUNK;
    int n1 = n0 + CHUNK;
    if (n1 > N_NODES) n1 = N_NODES;
    const int c = threadIdx.x;
    float acc = 0.0f;
    int curb = batch[n0];
    for (int n = n0; n < n1; ++n) {
        const int bb = batch[n];
        if (bb != curb) {
            atomicAdd(&out[curb * C_H + c], acc);
            acc = 0.0f;
            curb = bb;
        }
        acc += h[n * C_H + c];
    }
    atomicAdd(&out[curb * C_H + c], acc);
}

extern "C" void kernel_launch(void* const* d_in, const int* in_sizes, int n_in,
                              void* d_out, int out_size, void* d_ws, size_t ws_size,
                              hipStream_t stream) {
    const float* x       = (const float*)d_in[0];
    const float* pos     = (const float*)d_in[1];
    const int*   eidx    = (const int*)d_in[2];
    const int*   batch   = (const int*)d_in[3];
    const float* W_lin   = (const float*)d_in[4];
    const float* b_lin   = (const float*)d_in[5];

    float* h   = (float*)d_ws;
    float* agg = h + (size_t)N_NODES * C_H;

    const int* row = eidx;            // edge_index[0]
    const int* col = eidx + N_EDGES;  // edge_index[1]

    hipLaunchKernelGGL(lin0_kernel, dim3(N_NODES / 8), dim3(128), 0, stream,
                       x, W_lin, b_lin, h);

    for (int l = 0; l < 3; ++l) {
        const float* Wc = (const float*)d_in[6 + l * 6 + 0];
        const float* bc = (const float*)d_in[6 + l * 6 + 1];
        const float* Wn = (const float*)d_in[6 + l * 6 + 2];
        const float* bn = (const float*)d_in[6 + l * 6 + 3];
        const float* g  = (const float*)d_in[6 + l * 6 + 4];
        const float* be = (const float*)d_in[6 + l * 6 + 5];

        hipMemsetAsync(agg, 0, (size_t)N_NODES * C_H * sizeof(float), stream);
        hipLaunchKernelGGL(edge_kernel, dim3(N_EDGES / 256), dim3(256), 0, stream,
                           h, pos, row, col, Wc, bc, agg);
        hipLaunchKernelGGL(node_kernel, dim3(N_NODES / 16), dim3(128), 0, stream,
                           h, agg, Wn, bn, g, be);
    }

    hipMemsetAsync(d_out, 0, (size_t)NUM_GRAPHS * C_H * sizeof(float), stream);
    hipLaunchKernelGGL(pool_kernel, dim3((N_NODES + 249) / 250), dim3(128), 0, stream,
                       h, batch, (float*)d_out);
}

// Round 2
// 701.397 us; speedup vs baseline: 1.7903x; 1.7903x over previous
//
#include <hip/hip_runtime.h>
#include <math.h>

#define N_NODES 50000
#define N_EDGES 800000
#define NUM_GRAPHS 256
#define C_IN 64
#define C_H 128
#define D_COUNT 9
#define LRELU_SLOPE 0.01f
#define BN_EPS 1e-5f

__device__ __forceinline__ float silu_f(float a) {
    return a / (1.0f + __expf(-a));
}

// ---------------- CSR build (once per call; edge structure shared by all 3 layers) ---------

__global__ void hist_kernel(const int* __restrict__ col, int* __restrict__ counts) {
    const int e = blockIdx.x * 256 + threadIdx.x;
    if (e < N_EDGES) atomicAdd(&counts[col[e]], 1);
}

// single block, 1024 threads: exclusive scan counts[N_NODES] -> offsets[N_NODES+1], and copy to cur[]
__global__ void scan_kernel(const int* __restrict__ counts, int* __restrict__ offsets,
                            int* __restrict__ cur) {
    __shared__ int part[1024];
    const int t = threadIdx.x;
    const int CH = (N_NODES + 1023) / 1024;  // 49
    const int lo = t * CH;
    const int hi = min(lo + CH, N_NODES);
    int s = 0;
    for (int i = lo; i < hi; ++i) s += counts[i];
    part[t] = s;
    __syncthreads();
    for (int d = 1; d < 1024; d <<= 1) {
        int v = 0;
        if (t >= d) v = part[t - d];
        __syncthreads();
        part[t] += v;
        __syncthreads();
    }
    int base = (t == 0) ? 0 : part[t - 1];
    for (int i = lo; i < hi; ++i) {
        const int c = counts[i];
        offsets[i] = base;
        cur[i] = base;
        base += c;
    }
    if (t == 1023) offsets[N_NODES] = N_EDGES;
}

__global__ void scatter_kernel(const int* __restrict__ row, const int* __restrict__ col,
                               int* __restrict__ cur, int* __restrict__ row_csr) {
    const int e = blockIdx.x * 256 + threadIdx.x;
    if (e < N_EDGES) {
        const int p = atomicAdd(&cur[col[e]], 1);
        row_csr[p] = row[e];
    }
}

// ---------------- h = silu(x @ W_lin + b_lin) ----------------------------------------------
// block: 128 threads, 8 nodes per block
__global__ void lin0_kernel(const float* __restrict__ x, const float* __restrict__ W,
                            const float* __restrict__ b, float* __restrict__ h) {
    __shared__ float xs[8][C_IN];
    const int node0 = blockIdx.x * 8;
    const int t = threadIdx.x;
    for (int i = t; i < 8 * C_IN; i += 128)
        xs[i >> 6][i & 63] = x[node0 * C_IN + i];
    __syncthreads();
    float acc[8];
    const float bc = b[t];
#pragma unroll
    for (int n = 0; n < 8; ++n) acc[n] = bc;
    for (int k = 0; k < C_IN; ++k) {
        const float w = W[k * C_H + t];
#pragma unroll
        for (int n = 0; n < 8; ++n) acc[n] += xs[n][k] * w;
    }
#pragma unroll
    for (int n = 0; n < 8; ++n)
        h[(node0 + n) * C_H + t] = silu_f(acc[n]);
}

// ---------------- gather-aggregate: agg[n] = sum_{e: col==n} h[row_e] * radial_e -----------
// one block per node; 128 threads = channels; register accumulate, no atomics.
__global__ __launch_bounds__(128, 8) void aggregate_kernel(
        const float* __restrict__ h, const float* __restrict__ pos,
        const int* __restrict__ offsets, const int* __restrict__ row_csr,
        const float* __restrict__ Wc, const float* __restrict__ bc,
        float* __restrict__ agg) {
    __shared__ float rbf_s[128][D_COUNT];
    __shared__ int rows_s[128];
    const int node = blockIdx.x;
    const int t = threadIdx.x;  // channel
    const int start = offsets[node];
    const int end = offsets[node + 1];
    float wc[D_COUNT];
#pragma unroll
    for (int k = 0; k < D_COUNT; ++k) wc[k] = Wc[k * C_H + t];
    const float bcc = bc[t];
    const float px = pos[node * 3 + 0];
    const float py = pos[node * 3 + 1];
    const float pz = pos[node * 3 + 2];
    float acc = 0.0f;
    for (int base = start; base < end; base += 128) {
        const int m = min(128, end - base);
        __syncthreads();  // protect LDS reuse across chunk iterations
        if (t < m) {
            const int r = row_csr[base + t];
            rows_s[t] = r;
            const float dx = pos[r * 3 + 0] - px;
            const float dy = pos[r * 3 + 1] - py;
            const float dz = pos[r * 3 + 2] - pz;
            const float d = sqrtf(dx * dx + dy * dy + dz * dz);
#pragma unroll
            for (int k = 0; k < D_COUNT; ++k) {
                const float u = (d - 0.75f * (float)k) * 1.5f;  // sigma=6/9 -> 1/sigma=1.5
                rbf_s[t][k] = __expf(-u * u);
            }
        }
        __syncthreads();
        for (int j = 0; j < m; ++j) {
            float a = bcc;
#pragma unroll
            for (int k = 0; k < D_COUNT; ++k) a += rbf_s[j][k] * wc[k];
            const float radial = a / (1.0f + __expf(-a));
            acc += h[rows_s[j] * C_H + t] * radial;
        }
    }
    agg[node * C_H + t] = acc;
}

// ---------------- h = g * lrelu((h+agg) @ Wn + bn)/sqrt(1+eps) + be  (in place) -------------
__global__ void node_kernel(float* __restrict__ h, const float* __restrict__ agg,
                            const float* __restrict__ Wn, const float* __restrict__ bn,
                            const float* __restrict__ g, const float* __restrict__ be) {
    __shared__ float s[16][C_H];
    const int node0 = blockIdx.x * 16;
    const int t = threadIdx.x;
    for (int i = t; i < 16 * C_H; i += 128)
        s[i >> 7][i & 127] = h[node0 * C_H + i] + agg[node0 * C_H + i];
    __syncthreads();
    float acc[16];
    const float bnc = bn[t];
#pragma unroll
    for (int n = 0; n < 16; ++n) acc[n] = bnc;
    for (int k = 0; k < C_H; ++k) {
        const float w = Wn[k * C_H + t];
#pragma unroll
        for (int n = 0; n < 16; ++n) acc[n] += s[n][k] * w;
    }
    const float inv = 1.0f / sqrtf(1.0f + BN_EPS);
    const float gc = g[t] * inv;
    const float bec = be[t];
#pragma unroll
    for (int n = 0; n < 16; ++n) {
        float v = acc[n];
        v = v > 0.0f ? v : LRELU_SLOPE * v;
        h[(node0 + n) * C_H + t] = gc * v + bec;
    }
}

// ---------------- global_add_pool (batch sorted -> run-accumulate) ---------------------------
__global__ void pool_kernel(const float* __restrict__ h, const int* __restrict__ batch,
                            float* __restrict__ out) {
    const int CHUNK = 250;
    const int n0 = blockIdx.x * CHUNK;
    int n1 = n0 + CHUNK;
    if (n1 > N_NODES) n1 = N_NODES;
    const int c = threadIdx.x;
    float acc = 0.0f;
    int curb = batch[n0];
    for (int n = n0; n < n1; ++n) {
        const int bb = batch[n];
        if (bb != curb) {
            atomicAdd(&out[curb * C_H + c], acc);
            acc = 0.0f;
            curb = bb;
        }
        acc += h[n * C_H + c];
    }
    atomicAdd(&out[curb * C_H + c], acc);
}

extern "C" void kernel_launch(void* const* d_in, const int* in_sizes, int n_in,
                              void* d_out, int out_size, void* d_ws, size_t ws_size,
                              hipStream_t stream) {
    const float* x     = (const float*)d_in[0];
    const float* pos   = (const float*)d_in[1];
    const int*   eidx  = (const int*)d_in[2];
    const int*   batch = (const int*)d_in[3];
    const float* W_lin = (const float*)d_in[4];
    const float* b_lin = (const float*)d_in[5];

    // workspace layout (floats/ints, 4B each):
    float* h   = (float*)d_ws;                          // 6.4M
    float* agg = h + (size_t)N_NODES * C_H;             // 6.4M
    int* counts  = (int*)(agg + (size_t)N_NODES * C_H); // 50000
    int* offsets = counts + N_NODES;                    // 50001
    int* cur     = offsets + (N_NODES + 1);             // 50000
    int* row_csr = cur + N_NODES;                       // 800000

    const int* row = eidx;
    const int* col = eidx + N_EDGES;

    // CSR build (edge structure identical for all layers)
    hipMemsetAsync(counts, 0, N_NODES * sizeof(int), stream);
    hipLaunchKernelGGL(hist_kernel, dim3((N_EDGES + 255) / 256), dim3(256), 0, stream,
                       col, counts);
    hipLaunchKernelGGL(scan_kernel, dim3(1), dim3(1024), 0, stream,
                       counts, offsets, cur);
    hipLaunchKernelGGL(scatter_kernel, dim3((N_EDGES + 255) / 256), dim3(256), 0, stream,
                       row, col, cur, row_csr);

    hipLaunchKernelGGL(lin0_kernel, dim3(N_NODES / 8), dim3(128), 0, stream,
                       x, W_lin, b_lin, h);

    for (int l = 0; l < 3; ++l) {
        const float* Wc = (const float*)d_in[6 + l * 6 + 0];
        const float* bc = (const float*)d_in[6 + l * 6 + 1];
        const float* Wn = (const float*)d_in[6 + l * 6 + 2];
        const float* bn = (const float*)d_in[6 + l * 6 + 3];
        const float* g  = (const float*)d_in[6 + l * 6 + 4];
        const float* be = (const float*)d_in[6 + l * 6 + 5];

        hipLaunchKernelGGL(aggregate_kernel, dim3(N_NODES), dim3(128), 0, stream,
                           h, pos, offsets, row_csr, Wc, bc, agg);
        hipLaunchKernelGGL(node_kernel, dim3(N_NODES / 16), dim3(128), 0, stream,
                           h, agg, Wn, bn, g, be);
    }

    hipMemsetAsync(d_out, 0, (size_t)NUM_GRAPHS * C_H * sizeof(float), stream);
    hipLaunchKernelGGL(pool_kernel, dim3((N_NODES + 249) / 250), dim3(128), 0, stream,
                       h, batch, (float*)d_out);
}